// Round 11
// baseline (224.645 us; speedup 1.0000x reference)
//
#include <hip/hip_runtime.h>

// GCNConv: out = A_hat @ x @ W + b, A_hat = D^-1/2 (A + I) D^-1/2
// v15: scatter reworked for occupancy: SC_T=4096 + 1024-thread blocks (391
// blocks = 1.5/CU, 16 waves/block vs v14's 196x8; latency-bound kernel) and
// register-stash of src/dst (each edge word read exactly once). Rest = v14:
// k_gemm_hd (fused deg-hist + bf16 MFMA h'=dinv*xW, 128-row W reuse) ->
// k_sort_agg (LDS counting sort + dynamic-claim 16-lane-group gather,
// register accumulate, nt stores) — gather measured at its ~2.6TB/s L3 floor.
// (Round-10 resubmit: round-9 bench died on container infra, kernel unrun.)

#define SCAN_T 256
#define SCAN_E 1024
#define WPB 4
#define CAP 2560      // pairs per 128-node bucket (mean 2048, +11 sigma)
#define SC_T 4096     // edges per scatter block -> 391 blocks at E=1.6M

typedef __attribute__((ext_vector_type(8))) short short8;
typedef __attribute__((ext_vector_type(4))) float f32x4;

__device__ __forceinline__ unsigned short f2bf(float f) {
  unsigned int u = __float_as_uint(f);
  u += 0x7FFFu + ((u >> 16) & 1u);   // RNE
  return (unsigned short)(u >> 16);
}
__device__ __forceinline__ float bf_lo(unsigned int u) { return __uint_as_float(u << 16); }
__device__ __forceinline__ float bf_hi(unsigned int u) { return __uint_as_float(u & 0xFFFF0000u); }

// ======================= v15 primary path =======================

__global__ void k_zero(int* __restrict__ p, int m) {
  int i = blockIdx.x * blockDim.x + threadIdx.x;
  if (i < m) p[i] = 0;
}

// Bucket-scatter: pairs[b*CAP + slot] = (dst&127)<<17 | src. bucket = dst>>7.
// 1024 threads, 4 edges/thread (one int4 of src + one of dst, kept in regs).
__global__ void __launch_bounds__(1024) k_scatter(
    const int* __restrict__ ei, int* __restrict__ bcursor,
    int* __restrict__ pairs, int E, int B) {
  __shared__ int hist[1024];
  int t = threadIdx.x;
  if (t < B) hist[t] = 0;
  __syncthreads();
  int e0 = blockIdx.x * SC_T;
  int eend = min(e0 + SC_T, E);
  int e = e0 + t * 4;
  int4 d = make_int4(0, 0, 0, 0), s = make_int4(0, 0, 0, 0);
  int nv = 0;                        // valid edges for this thread (0, 4, or tail)
  if (e + 3 < eend) {
    d = *(const int4*)(ei + E + e);
    s = *(const int4*)(ei + e);
    nv = 4;
    atomicAdd(&hist[((unsigned)d.x) >> 7], 1);
    atomicAdd(&hist[((unsigned)d.y) >> 7], 1);
    atomicAdd(&hist[((unsigned)d.z) >> 7], 1);
    atomicAdd(&hist[((unsigned)d.w) >> 7], 1);
  } else if (e < eend) {
    nv = eend - e;
    int* dd = &d.x; int* ss = &s.x;
    for (int q = 0; q < nv; ++q) {
      dd[q] = ei[E + e + q];
      ss[q] = ei[e + q];
      atomicAdd(&hist[((unsigned)dd[q]) >> 7], 1);
    }
  }
  __syncthreads();
  if (t < B) {
    int c = hist[t];
    hist[t] = c ? atomicAdd(&bcursor[t], c) : 0;  // base within bucket
  }
  __syncthreads();
  if (nv == 4) {
    int b0 = ((unsigned)d.x) >> 7; int p0 = atomicAdd(&hist[b0], 1);
    if (p0 < CAP) pairs[(size_t)b0 * CAP + p0] = ((d.x & 127) << 17) | s.x;
    int b1 = ((unsigned)d.y) >> 7; int p1 = atomicAdd(&hist[b1], 1);
    if (p1 < CAP) pairs[(size_t)b1 * CAP + p1] = ((d.y & 127) << 17) | s.y;
    int b2 = ((unsigned)d.z) >> 7; int p2 = atomicAdd(&hist[b2], 1);
    if (p2 < CAP) pairs[(size_t)b2 * CAP + p2] = ((d.z & 127) << 17) | s.z;
    int b3 = ((unsigned)d.w) >> 7; int p3 = atomicAdd(&hist[b3], 1);
    if (p3 < CAP) pairs[(size_t)b3 * CAP + p3] = ((d.w & 127) << 17) | s.w;
  } else if (nv > 0) {
    const int* dd = &d.x; const int* ss = &s.x;
    for (int q = 0; q < nv; ++q) {
      int b0 = ((unsigned)dd[q]) >> 7; int p0 = atomicAdd(&hist[b0], 1);
      if (p0 < CAP) pairs[(size_t)b0 * CAP + p0] = ((dd[q] & 127) << 17) | ss[q];
    }
  }
}

// Fused deg + GEMM. Block b == bucket b == rows b*128..b*128+127.
// Phase A: LDS hist of bucket pairs (-> dinv local) || stage W^T bf16.
// Phase B: bf16 MFMA h' = dinv * (x @ W), two 64-row halves reuse W tile.
__global__ void __launch_bounds__(256) k_gemm_hd(
    const float* __restrict__ x, const float* __restrict__ W,
    const int* __restrict__ pairs, const int* __restrict__ bcursor,
    unsigned short* __restrict__ h, int n) {
  __shared__ alignas(16) unsigned short Wt[128][136];
  __shared__ int hist[128];
  int t = threadIdx.x;
  int b = blockIdx.x;
  if (t < 128) hist[t] = 0;
  __syncthreads();
  int cnt = min(bcursor[b], CAP);
  const int* __restrict__ gp = pairs + (size_t)b * CAP;
  for (int i = t; i < cnt; i += 256) atomicAdd(&hist[gp[i] >> 17], 1);
  // stage W^T as bf16: read W[kg*4+i][nn] coalesced, write 4 k-consecutive
#pragma unroll
  for (int p = 0; p < 16; ++p) {
    int task = p * 256 + t;
    int kg = task >> 7, nn = task & 127;
    float w0 = W[(kg * 4 + 0) * 128 + nn];
    float w1 = W[(kg * 4 + 1) * 128 + nn];
    float w2 = W[(kg * 4 + 2) * 128 + nn];
    float w3 = W[(kg * 4 + 3) * 128 + nn];
    ushort4 u;
    u.x = f2bf(w0); u.y = f2bf(w1); u.z = f2bf(w2); u.w = f2bf(w3);
    *(ushort4*)&Wt[nn][kg * 4] = u;
  }
  __syncthreads();
  int w = t >> 6, lane = t & 63;
  int q = lane >> 4, m = lane & 15;
#pragma unroll
  for (int rep = 0; rep < 2; ++rep) {
    int lbase = rep * 64 + w * 16;          // local row base within bucket
    int r0 = (b << 7) + lbase;
    f32x4 acc[8];
#pragma unroll
    for (int nt = 0; nt < 8; ++nt) acc[nt] = (f32x4){0.f, 0.f, 0.f, 0.f};
    float dscale[4];
#pragma unroll
    for (int rg = 0; rg < 4; ++rg)
      dscale[rg] = rsqrtf((float)hist[lbase + q * 4 + rg] + 1.0f);
#pragma unroll
    for (int ks = 0; ks < 4; ++ks) {
      int row = r0 + m;
      row = row < n ? row : n - 1;
      const float* xp = x + (size_t)row * 128 + ks * 32 + q * 8;
      float4 a0 = *(const float4*)xp;
      float4 a1 = *(const float4*)(xp + 4);
      short8 af;
      af[0] = (short)f2bf(a0.x); af[1] = (short)f2bf(a0.y);
      af[2] = (short)f2bf(a0.z); af[3] = (short)f2bf(a0.w);
      af[4] = (short)f2bf(a1.x); af[5] = (short)f2bf(a1.y);
      af[6] = (short)f2bf(a1.z); af[7] = (short)f2bf(a1.w);
#pragma unroll
      for (int nt = 0; nt < 8; ++nt) {
        short8 bf = *(const short8*)&Wt[nt * 16 + m][ks * 32 + q * 8];
        acc[nt] = __builtin_amdgcn_mfma_f32_16x16x32_bf16(af, bf, acc[nt], 0, 0, 0);
      }
    }
#pragma unroll
    for (int nt = 0; nt < 8; ++nt)
#pragma unroll
      for (int rg = 0; rg < 4; ++rg) {
        int r = r0 + q * 4 + rg;
        if (r < n) h[(size_t)r * 128 + nt * 16 + m] = f2bf(acc[nt][rg] * dscale[rg]);
      }
  }
}

// Fused sort + aggregate for a 128-node bucket, 512 threads. Slim LDS:
// no pb[] copy (placement pass re-reads pairs from global, L2-hot).
// Phase 2: 32 16-lane groups dynamically claim nodes; gather h[src] rows
// (uint4, 8-deep unroll, register accumulate); out = dinv*a + bias, nt store.
__global__ void __launch_bounds__(512) k_sort_agg(
    const int* __restrict__ pairs, const int* __restrict__ bcursor,
    const uint4* __restrict__ h4, const float* __restrict__ bias,
    float* __restrict__ out, int n) {
  __shared__ int sorted[CAP];
  __shared__ int hist[128], base_[128], cur[128];
  __shared__ int nextn;
  int t = threadIdx.x;
  int b = blockIdx.x;
  if (t < 128) { hist[t] = 0; cur[t] = 0; }
  if (t == 0) nextn = 0;
  __syncthreads();
  int cnt = min(bcursor[b], CAP);
  const int* __restrict__ gp = pairs + (size_t)b * CAP;
  for (int i = t; i < cnt; i += 512) atomicAdd(&hist[gp[i] >> 17], 1);
  __syncthreads();
  // exclusive scan of hist[128] via LDS Hillis-Steele
  if (t < 128) base_[t] = hist[t];
  __syncthreads();
#pragma unroll
  for (int d = 1; d < 128; d <<= 1) {
    int v = (t < 128 && t >= d) ? base_[t - d] : 0;
    __syncthreads();
    if (t < 128) base_[t] += v;
    __syncthreads();
  }
  if (t < 128) base_[t] -= hist[t];
  __syncthreads();
  for (int i = t; i < cnt; i += 512) {
    int p = gp[i];
    int d = p >> 17;
    int pos = base_[d] + atomicAdd(&cur[d], 1);
    sorted[pos] = p & 0x1FFFF;
  }
  __syncthreads();

  // ---- phase 2: gather-aggregate with dynamic node claiming ----
  int lane = t & 63;
  int ln = lane & 15;
  int nbase = b << 7;
  for (;;) {
    int row = 0;
    if (ln == 0) row = atomicAdd(&nextn, 1);
    row = __shfl(row, lane & 48, 64);   // broadcast to the 16-lane group
    if (row >= 128) break;
    int node = nbase + row;
    bool act = node < n;
    uint4 sp = make_uint4(0u, 0u, 0u, 0u);
    if (act) sp = h4[(size_t)node * 16 + ln];  // self term
    float a[8];
    a[0] = bf_lo(sp.x); a[1] = bf_hi(sp.x);
    a[2] = bf_lo(sp.y); a[3] = bf_hi(sp.y);
    a[4] = bf_lo(sp.z); a[5] = bf_hi(sp.z);
    a[6] = bf_lo(sp.w); a[7] = bf_hi(sp.w);
    int s = base_[row];
    int cd = hist[row];
    int end = s + cd;
    for (; s + 8 <= end; s += 8) {
      uint4 u[8];
#pragma unroll
      for (int k = 0; k < 8; ++k) {
        int idx = sorted[s + k];
        u[k] = h4[(size_t)idx * 16 + ln];
      }
#pragma unroll
      for (int k = 0; k < 8; ++k) {
        a[0] += bf_lo(u[k].x); a[1] += bf_hi(u[k].x);
        a[2] += bf_lo(u[k].y); a[3] += bf_hi(u[k].y);
        a[4] += bf_lo(u[k].z); a[5] += bf_hi(u[k].z);
        a[6] += bf_lo(u[k].w); a[7] += bf_hi(u[k].w);
      }
    }
    for (; s + 4 <= end; s += 4) {
      uint4 u[4];
#pragma unroll
      for (int k = 0; k < 4; ++k) {
        int idx = sorted[s + k];
        u[k] = h4[(size_t)idx * 16 + ln];
      }
#pragma unroll
      for (int k = 0; k < 4; ++k) {
        a[0] += bf_lo(u[k].x); a[1] += bf_hi(u[k].x);
        a[2] += bf_lo(u[k].y); a[3] += bf_hi(u[k].y);
        a[4] += bf_lo(u[k].z); a[5] += bf_hi(u[k].z);
        a[6] += bf_lo(u[k].w); a[7] += bf_hi(u[k].w);
      }
    }
    for (; s < end; ++s) {
      int idx = sorted[s];
      uint4 u = h4[(size_t)idx * 16 + ln];
      a[0] += bf_lo(u.x); a[1] += bf_hi(u.x);
      a[2] += bf_lo(u.y); a[3] += bf_hi(u.y);
      a[4] += bf_lo(u.z); a[5] += bf_hi(u.z);
      a[6] += bf_lo(u.w); a[7] += bf_hi(u.w);
    }
    if (act) {
      float di = rsqrtf((float)cd + 1.0f);
      float4 b0 = ((const float4*)bias)[2 * ln];
      float4 b1 = ((const float4*)bias)[2 * ln + 1];
      f32x4 r0, r1;
      r0[0] = fmaf(a[0], di, b0.x); r0[1] = fmaf(a[1], di, b0.y);
      r0[2] = fmaf(a[2], di, b0.z); r0[3] = fmaf(a[3], di, b0.w);
      r1[0] = fmaf(a[4], di, b1.x); r1[1] = fmaf(a[5], di, b1.y);
      r1[2] = fmaf(a[6], di, b1.z); r1[3] = fmaf(a[7], di, b1.w);
      f32x4* op = (f32x4*)(out + (size_t)node * 128 + ln * 8);
      __builtin_nontemporal_store(r0, op);
      __builtin_nontemporal_store(r1, op + 1);
    }
  }
}

// ======================= round-3 CSR fallback =======================

__global__ void k_init(int* __restrict__ cnt, int n) {
  int i = blockIdx.x * blockDim.x + threadIdx.x;
  if (i < n) cnt[i] = 0;
}

__global__ void k_count4(const int* __restrict__ ei, int* __restrict__ cnt, int E) {
  int i = blockIdx.x * blockDim.x + threadIdx.x;
  int e = i * 4;
  if (e + 3 < E) {
    int4 d = *(const int4*)(ei + E + e);
    atomicAdd(&cnt[d.x], 1); atomicAdd(&cnt[d.y], 1);
    atomicAdd(&cnt[d.z], 1); atomicAdd(&cnt[d.w], 1);
  } else {
    for (; e < E; ++e) atomicAdd(&cnt[ei[E + e]], 1);
  }
}

__global__ void k_scan_local(const int* __restrict__ cnt, int* __restrict__ offs,
                             int* __restrict__ bsums, int n) {
  __shared__ int sh[SCAN_T];
  int t = threadIdx.x;
  int base = blockIdx.x * SCAN_E + t * 4;
  int v0 = 0, v1 = 0, v2 = 0, v3 = 0;
  if (base + 0 < n) v0 = cnt[base + 0];
  if (base + 1 < n) v1 = cnt[base + 1];
  if (base + 2 < n) v2 = cnt[base + 2];
  if (base + 3 < n) v3 = cnt[base + 3];
  int sum = v0 + v1 + v2 + v3;
  sh[t] = sum;
  __syncthreads();
  for (int d = 1; d < SCAN_T; d <<= 1) {
    int xv = (t >= d) ? sh[t - d] : 0;
    __syncthreads();
    sh[t] += xv;
    __syncthreads();
  }
  int run = sh[t] - sum;
  if (base + 0 < n) offs[base + 0] = run; run += v0;
  if (base + 1 < n) offs[base + 1] = run; run += v1;
  if (base + 2 < n) offs[base + 2] = run; run += v2;
  if (base + 3 < n) offs[base + 3] = run;
  if (t == SCAN_T - 1) bsums[blockIdx.x] = sh[t];
}

__global__ void k_scan_bsums(int* __restrict__ bsums, int nb) {
  __shared__ int sh[SCAN_T];
  int t = threadIdx.x;
  int v = (t < nb) ? bsums[t] : 0;
  sh[t] = v;
  __syncthreads();
  for (int d = 1; d < SCAN_T; d <<= 1) {
    int xv = (t >= d) ? sh[t - d] : 0;
    __syncthreads();
    sh[t] += xv;
    __syncthreads();
  }
  if (t < nb) bsums[t] = sh[t] - v;
}

__global__ void k_scan_finish(int* __restrict__ offs, const int* __restrict__ bsums,
                              const int* __restrict__ cnt, int* __restrict__ offs2,
                              float* __restrict__ dinv, int n) {
  int i = blockIdx.x * blockDim.x + threadIdx.x;
  if (i < n) {
    int o = offs[i] + bsums[i / SCAN_E];
    offs[i] = o;
    offs2[i] = o;
    dinv[i] = rsqrtf((float)cnt[i] + 1.0f);
  }
}

__global__ void k_fill4(const int* __restrict__ ei, int* __restrict__ offs2,
                        int* __restrict__ csr, int E) {
  int i = blockIdx.x * blockDim.x + threadIdx.x;
  int e = i * 4;
  if (e + 3 < E) {
    int4 s = *(const int4*)(ei + e);
    int4 d = *(const int4*)(ei + E + e);
    csr[atomicAdd(&offs2[d.x], 1)] = s.x;
    csr[atomicAdd(&offs2[d.y], 1)] = s.y;
    csr[atomicAdd(&offs2[d.z], 1)] = s.z;
    csr[atomicAdd(&offs2[d.w], 1)] = s.w;
  } else {
    for (; e < E; ++e) csr[atomicAdd(&offs2[ei[E + e]], 1)] = ei[e];
  }
}

__global__ void __launch_bounds__(256) k_gemm_h(
    const float* __restrict__ x, const float* __restrict__ W,
    const float* __restrict__ dinv, unsigned short* __restrict__ h, int n) {
  __shared__ alignas(16) unsigned short Wt[128][136];
  int t = threadIdx.x;
#pragma unroll
  for (int p = 0; p < 16; ++p) {
    int task = p * 256 + t;
    int kg = task >> 7, nn = task & 127;
    float w0 = W[(kg * 4 + 0) * 128 + nn];
    float w1 = W[(kg * 4 + 1) * 128 + nn];
    float w2 = W[(kg * 4 + 2) * 128 + nn];
    float w3 = W[(kg * 4 + 3) * 128 + nn];
    ushort4 u;
    u.x = f2bf(w0); u.y = f2bf(w1); u.z = f2bf(w2); u.w = f2bf(w3);
    *(ushort4*)&Wt[nn][kg * 4] = u;
  }
  __syncthreads();
  int w = t >> 6, lane = t & 63;
  int q = lane >> 4, m = lane & 15;
  int r0 = blockIdx.x * 64 + w * 16;
  f32x4 acc[8];
#pragma unroll
  for (int nt = 0; nt < 8; ++nt) acc[nt] = (f32x4){0.f, 0.f, 0.f, 0.f};
  float dscale[4];
#pragma unroll
  for (int rg = 0; rg < 4; ++rg) {
    int r = r0 + q * 4 + rg;
    dscale[rg] = dinv[r < n ? r : n - 1];
  }
#pragma unroll
  for (int ks = 0; ks < 4; ++ks) {
    int row = r0 + m;
    row = row < n ? row : n - 1;
    const float* xp = x + (size_t)row * 128 + ks * 32 + q * 8;
    float4 a0 = *(const float4*)xp;
    float4 a1 = *(const float4*)(xp + 4);
    short8 af;
    af[0] = (short)f2bf(a0.x); af[1] = (short)f2bf(a0.y);
    af[2] = (short)f2bf(a0.z); af[3] = (short)f2bf(a0.w);
    af[4] = (short)f2bf(a1.x); af[5] = (short)f2bf(a1.y);
    af[6] = (short)f2bf(a1.z); af[7] = (short)f2bf(a1.w);
#pragma unroll
    for (int nt = 0; nt < 8; ++nt) {
      short8 bf = *(const short8*)&Wt[nt * 16 + m][ks * 32 + q * 8];
      acc[nt] = __builtin_amdgcn_mfma_f32_16x16x32_bf16(af, bf, acc[nt], 0, 0, 0);
    }
  }
#pragma unroll
  for (int nt = 0; nt < 8; ++nt)
#pragma unroll
    for (int rg = 0; rg < 4; ++rg) {
      int r = r0 + q * 4 + rg;
      if (r < n) h[(size_t)r * 128 + nt * 16 + m] = f2bf(acc[nt][rg] * dscale[rg]);
    }
}

__global__ void __launch_bounds__(256) k_agg_bias_csr(
    const unsigned int* __restrict__ h2, const float* __restrict__ dinv,
    const int* __restrict__ offs, const int* __restrict__ cnt,
    const int* __restrict__ csr, const float* __restrict__ bias,
    float* __restrict__ out, int n) {
  int node = blockIdx.x * WPB + (threadIdx.x >> 6);
  int lane = threadIdx.x & 63;
  if (node >= n) return;
  unsigned int sp = h2[(size_t)node * 64 + lane];
  float ax = bf_lo(sp), ay = bf_hi(sp);
  int s = offs[node];
  int end = s + cnt[node];
  for (; s + 8 <= end; s += 8) {
    int i0 = csr[s + 0], i1 = csr[s + 1], i2 = csr[s + 2], i3 = csr[s + 3];
    int i4 = csr[s + 4], i5 = csr[s + 5], i6 = csr[s + 6], i7 = csr[s + 7];
    unsigned int u0 = h2[(size_t)i0 * 64 + lane];
    unsigned int u1 = h2[(size_t)i1 * 64 + lane];
    unsigned int u2 = h2[(size_t)i2 * 64 + lane];
    unsigned int u3 = h2[(size_t)i3 * 64 + lane];
    unsigned int u4 = h2[(size_t)i4 * 64 + lane];
    unsigned int u5 = h2[(size_t)i5 * 64 + lane];
    unsigned int u6 = h2[(size_t)i6 * 64 + lane];
    unsigned int u7 = h2[(size_t)i7 * 64 + lane];
    ax += (bf_lo(u0) + bf_lo(u1)) + (bf_lo(u2) + bf_lo(u3)) +
          (bf_lo(u4) + bf_lo(u5)) + (bf_lo(u6) + bf_lo(u7));
    ay += (bf_hi(u0) + bf_hi(u1)) + (bf_hi(u2) + bf_hi(u3)) +
          (bf_hi(u4) + bf_hi(u5)) + (bf_hi(u6) + bf_hi(u7));
  }
  for (; s < end; ++s) {
    unsigned int u = h2[(size_t)csr[s] * 64 + lane];
    ax += bf_lo(u); ay += bf_hi(u);
  }
  float di = dinv[node];
  float2 bb = ((const float2*)bias)[lane];
  float2 r;
  r.x = fmaf(ax, di, bb.x);
  r.y = fmaf(ay, di, bb.y);
  ((float2*)out)[(size_t)node * 64 + lane] = r;
}

extern "C" void kernel_launch(void* const* d_in, const int* in_sizes, int n_in,
                              void* d_out, int out_size, void* d_ws, size_t ws_size,
                              hipStream_t stream) {
  const float* x = (const float*)d_in[0];
  const int* ei = (const int*)d_in[1];   // harness delivers integers as int32
  const float* Wm = (const float*)d_in[2];
  const float* bias = (const float*)d_in[3];
  float* out = (float*)d_out;

  int N = in_sizes[0] / 128;
  int E = in_sizes[1] / 2;
  int NB64 = (N + 63) >> 6;
  int NB128 = (N + 127) >> 7;

  int nb_n = (N + 255) / 256;
  int nb_e4 = ((E + 3) / 4 + 255) / 256;

  // ---- v15: bcursor[1024] | pairs[NB128*CAP] | h[N*128 bf16] ----
  size_t off_pairs = 4096;
  size_t off_h = (off_pairs + (size_t)NB128 * CAP * 4 + 255) & ~(size_t)255;
  size_t need15 = off_h + (size_t)N * 256;

  if (ws_size >= need15 && N <= (1 << 17) && NB128 <= 1024) {
    char* p = (char*)d_ws;
    int* bcursor = (int*)p;
    int* pairs = (int*)(p + off_pairs);
    unsigned short* h = (unsigned short*)(p + off_h);

    k_zero<<<4, 256, 0, stream>>>(bcursor, 1024);
    k_scatter<<<(E + SC_T - 1) / SC_T, 1024, 0, stream>>>(ei, bcursor, pairs, E, NB128);
    k_gemm_hd<<<NB128, 256, 0, stream>>>(x, Wm, pairs, bcursor, h, N);
    k_sort_agg<<<NB128, 512, 0, stream>>>(pairs, bcursor, (const uint4*)h, bias, out, N);
    return;
  }

  // ---- round-3 CSR fallback ----
  char* p = (char*)d_ws;
  int* cnt = (int*)p;        p += (size_t)N * 4;
  int* offs = (int*)p;       p += (size_t)N * 4;
  int* offs2 = (int*)p;      p += (size_t)N * 4;
  float* dinv = (float*)p;   p += (size_t)N * 4;
  int* bsums = (int*)p;      p += 1024;
  int* csr = (int*)p;        p += (size_t)E * 4;
  unsigned short* h = (unsigned short*)p;

  int nb_scan = (N + SCAN_E - 1) / SCAN_E;

  k_init<<<nb_n, 256, 0, stream>>>(cnt, N);
  k_count4<<<nb_e4, 256, 0, stream>>>(ei, cnt, E);
  k_scan_local<<<nb_scan, SCAN_T, 0, stream>>>(cnt, offs, bsums, N);
  k_scan_bsums<<<1, SCAN_T, 0, stream>>>(bsums, nb_scan);
  k_scan_finish<<<nb_n, 256, 0, stream>>>(offs, bsums, cnt, offs2, dinv, N);
  k_fill4<<<nb_e4, 256, 0, stream>>>(ei, offs2, csr, E);
  k_gemm_h<<<NB64, 256, 0, stream>>>(x, Wm, dinv, h, N);
  k_agg_bias_csr<<<(N + WPB - 1) / WPB, 256, 0, stream>>>(
      (const unsigned int*)h, dinv, offs, cnt, csr, bias, out, N);
}

// Round 12
// 205.716 us; speedup vs baseline: 1.0920x; 1.0920x over previous
//
#include <hip/hip_runtime.h>

// GCNConv: out = A_hat @ x @ W + b, A_hat = D^-1/2 (A + I) D^-1/2
// v16: v14 pipeline (proven 204us) + coalesced h writeback in k_gemm_hd:
// acc -> LDS hbuf[64][136] -> uint4 global stores (v14 wrote 25.6MB of h via
// per-lane 2B ushort stores, <=32B/transaction). Scatter reverted to v14's
// 512-thread SC_T=8192 form (v15's 1024-thread variant was clock-normalized
// neutral). k_sort_agg unchanged (measured at its ~2.6TB/s L3-gather floor).

#define SCAN_T 256
#define SCAN_E 1024
#define WPB 4
#define CAP 2560      // pairs per 128-node bucket (mean 2048, +11 sigma)
#define SC_T 8192     // edges per scatter block -> 196 blocks at E=1.6M

typedef __attribute__((ext_vector_type(8))) short short8;
typedef __attribute__((ext_vector_type(4))) float f32x4;

__device__ __forceinline__ unsigned short f2bf(float f) {
  unsigned int u = __float_as_uint(f);
  u += 0x7FFFu + ((u >> 16) & 1u);   // RNE
  return (unsigned short)(u >> 16);
}
__device__ __forceinline__ float bf_lo(unsigned int u) { return __uint_as_float(u << 16); }
__device__ __forceinline__ float bf_hi(unsigned int u) { return __uint_as_float(u & 0xFFFF0000u); }

// ======================= v16 primary path =======================

__global__ void k_zero(int* __restrict__ p, int m) {
  int i = blockIdx.x * blockDim.x + threadIdx.x;
  if (i < m) p[i] = 0;
}

// Bucket-scatter: pairs[b*CAP + slot] = (dst&127)<<17 | src. bucket = dst>>7.
__global__ void __launch_bounds__(512) k_scatter(
    const int* __restrict__ ei, int* __restrict__ bcursor,
    int* __restrict__ pairs, int E, int B) {
  __shared__ int hist[1024];
  int t = threadIdx.x;
  for (int b = t; b < B; b += 512) hist[b] = 0;
  __syncthreads();
  int e0 = blockIdx.x * SC_T;
  int eend = min(e0 + SC_T, E);
  for (int e = e0 + t * 4; e < eend; e += 2048) {
    if (e + 3 < eend) {
      int4 d = *(const int4*)(ei + E + e);
      atomicAdd(&hist[((unsigned)d.x) >> 7], 1);
      atomicAdd(&hist[((unsigned)d.y) >> 7], 1);
      atomicAdd(&hist[((unsigned)d.z) >> 7], 1);
      atomicAdd(&hist[((unsigned)d.w) >> 7], 1);
    } else {
      for (int q = e; q < eend; ++q) atomicAdd(&hist[((unsigned)ei[E + q]) >> 7], 1);
    }
  }
  __syncthreads();
  for (int b = t; b < B; b += 512) {
    int c = hist[b];
    hist[b] = c ? atomicAdd(&bcursor[b], c) : 0;  // base within bucket
  }
  __syncthreads();
  for (int e = e0 + t * 4; e < eend; e += 2048) {
    if (e + 3 < eend) {
      int4 s = *(const int4*)(ei + e);
      int4 d = *(const int4*)(ei + E + e);
      int b0 = ((unsigned)d.x) >> 7; int p0 = atomicAdd(&hist[b0], 1);
      if (p0 < CAP) pairs[(size_t)b0 * CAP + p0] = ((d.x & 127) << 17) | s.x;
      int b1 = ((unsigned)d.y) >> 7; int p1 = atomicAdd(&hist[b1], 1);
      if (p1 < CAP) pairs[(size_t)b1 * CAP + p1] = ((d.y & 127) << 17) | s.y;
      int b2 = ((unsigned)d.z) >> 7; int p2 = atomicAdd(&hist[b2], 1);
      if (p2 < CAP) pairs[(size_t)b2 * CAP + p2] = ((d.z & 127) << 17) | s.z;
      int b3 = ((unsigned)d.w) >> 7; int p3 = atomicAdd(&hist[b3], 1);
      if (p3 < CAP) pairs[(size_t)b3 * CAP + p3] = ((d.w & 127) << 17) | s.w;
    } else {
      for (int q = e; q < eend; ++q) {
        int dst = ei[E + q], src = ei[q];
        int b0 = ((unsigned)dst) >> 7; int p0 = atomicAdd(&hist[b0], 1);
        if (p0 < CAP) pairs[(size_t)b0 * CAP + p0] = ((dst & 127) << 17) | src;
      }
    }
  }
}

// Fused deg + GEMM. Block b == bucket b == rows b*128..b*128+127.
// Phase A: LDS hist of bucket pairs (-> dinv local) || stage W^T bf16.
// Phase B: bf16 MFMA h' = dinv * (x @ W), two 64-row halves reuse W tile.
// Writeback via LDS hbuf -> coalesced uint4 stores (v16 change).
__global__ void __launch_bounds__(256) k_gemm_hd(
    const float* __restrict__ x, const float* __restrict__ W,
    const int* __restrict__ pairs, const int* __restrict__ bcursor,
    unsigned short* __restrict__ h, int n) {
  __shared__ alignas(16) unsigned short Wt[128][136];
  __shared__ alignas(16) unsigned short hbuf[64][136];
  __shared__ int hist[128];
  int t = threadIdx.x;
  int b = blockIdx.x;
  if (t < 128) hist[t] = 0;
  __syncthreads();
  int cnt = min(bcursor[b], CAP);
  const int* __restrict__ gp = pairs + (size_t)b * CAP;
  for (int i = t; i < cnt; i += 256) atomicAdd(&hist[gp[i] >> 17], 1);
  // stage W^T as bf16: read W[kg*4+i][nn] coalesced, write 4 k-consecutive
#pragma unroll
  for (int p = 0; p < 16; ++p) {
    int task = p * 256 + t;
    int kg = task >> 7, nn = task & 127;
    float w0 = W[(kg * 4 + 0) * 128 + nn];
    float w1 = W[(kg * 4 + 1) * 128 + nn];
    float w2 = W[(kg * 4 + 2) * 128 + nn];
    float w3 = W[(kg * 4 + 3) * 128 + nn];
    ushort4 u;
    u.x = f2bf(w0); u.y = f2bf(w1); u.z = f2bf(w2); u.w = f2bf(w3);
    *(ushort4*)&Wt[nn][kg * 4] = u;
  }
  __syncthreads();
  int w = t >> 6, lane = t & 63;
  int q = lane >> 4, m = lane & 15;
#pragma unroll
  for (int rep = 0; rep < 2; ++rep) {
    int lbase = rep * 64 + w * 16;          // local row base within bucket
    int r0 = (b << 7) + lbase;
    f32x4 acc[8];
#pragma unroll
    for (int nt = 0; nt < 8; ++nt) acc[nt] = (f32x4){0.f, 0.f, 0.f, 0.f};
    float dscale[4];
#pragma unroll
    for (int rg = 0; rg < 4; ++rg)
      dscale[rg] = rsqrtf((float)hist[lbase + q * 4 + rg] + 1.0f);
#pragma unroll
    for (int ks = 0; ks < 4; ++ks) {
      int row = r0 + m;
      row = row < n ? row : n - 1;
      const float* xp = x + (size_t)row * 128 + ks * 32 + q * 8;
      float4 a0 = *(const float4*)xp;
      float4 a1 = *(const float4*)(xp + 4);
      short8 af;
      af[0] = (short)f2bf(a0.x); af[1] = (short)f2bf(a0.y);
      af[2] = (short)f2bf(a0.z); af[3] = (short)f2bf(a0.w);
      af[4] = (short)f2bf(a1.x); af[5] = (short)f2bf(a1.y);
      af[6] = (short)f2bf(a1.z); af[7] = (short)f2bf(a1.w);
#pragma unroll
      for (int nt = 0; nt < 8; ++nt) {
        short8 bf = *(const short8*)&Wt[nt * 16 + m][ks * 32 + q * 8];
        acc[nt] = __builtin_amdgcn_mfma_f32_16x16x32_bf16(af, bf, acc[nt], 0, 0, 0);
      }
    }
    // stage acc -> hbuf (2-way-conflict LDS 2B writes, free)
#pragma unroll
    for (int nt = 0; nt < 8; ++nt)
#pragma unroll
      for (int rg = 0; rg < 4; ++rg)
        hbuf[w * 16 + q * 4 + rg][nt * 16 + m] = f2bf(acc[nt][rg] * dscale[rg]);
    __syncthreads();
    // coalesced writeback: each thread writes 64B (4x uint4) of one row
    {
      int lrow = t >> 2;            // 0..63
      int chunk = t & 3;            // 0..3
      int gr = (b << 7) + rep * 64 + lrow;
      if (gr < n) {
        const uint4* srcp = (const uint4*)&hbuf[lrow][chunk * 32];
        uint4* dstp = (uint4*)(h + (size_t)gr * 128 + chunk * 32);
        dstp[0] = srcp[0]; dstp[1] = srcp[1];
        dstp[2] = srcp[2]; dstp[3] = srcp[3];
      }
    }
    __syncthreads();
  }
}

// Fused sort + aggregate for a 128-node bucket, 512 threads. Slim LDS:
// no pb[] copy (placement pass re-reads pairs from global, L2-hot).
// Phase 2: 32 16-lane groups dynamically claim nodes; gather h[src] rows
// (uint4, 8-deep unroll, register accumulate); out = dinv*a + bias, nt store.
__global__ void __launch_bounds__(512) k_sort_agg(
    const int* __restrict__ pairs, const int* __restrict__ bcursor,
    const uint4* __restrict__ h4, const float* __restrict__ bias,
    float* __restrict__ out, int n) {
  __shared__ int sorted[CAP];
  __shared__ int hist[128], base_[128], cur[128];
  __shared__ int nextn;
  int t = threadIdx.x;
  int b = blockIdx.x;
  if (t < 128) { hist[t] = 0; cur[t] = 0; }
  if (t == 0) nextn = 0;
  __syncthreads();
  int cnt = min(bcursor[b], CAP);
  const int* __restrict__ gp = pairs + (size_t)b * CAP;
  for (int i = t; i < cnt; i += 512) atomicAdd(&hist[gp[i] >> 17], 1);
  __syncthreads();
  // exclusive scan of hist[128] via LDS Hillis-Steele
  if (t < 128) base_[t] = hist[t];
  __syncthreads();
#pragma unroll
  for (int d = 1; d < 128; d <<= 1) {
    int v = (t < 128 && t >= d) ? base_[t - d] : 0;
    __syncthreads();
    if (t < 128) base_[t] += v;
    __syncthreads();
  }
  if (t < 128) base_[t] -= hist[t];
  __syncthreads();
  for (int i = t; i < cnt; i += 512) {
    int p = gp[i];
    int d = p >> 17;
    int pos = base_[d] + atomicAdd(&cur[d], 1);
    sorted[pos] = p & 0x1FFFF;
  }
  __syncthreads();

  // ---- phase 2: gather-aggregate with dynamic node claiming ----
  int lane = t & 63;
  int ln = lane & 15;
  int nbase = b << 7;
  for (;;) {
    int row = 0;
    if (ln == 0) row = atomicAdd(&nextn, 1);
    row = __shfl(row, lane & 48, 64);   // broadcast to the 16-lane group
    if (row >= 128) break;
    int node = nbase + row;
    bool act = node < n;
    uint4 sp = make_uint4(0u, 0u, 0u, 0u);
    if (act) sp = h4[(size_t)node * 16 + ln];  // self term
    float a[8];
    a[0] = bf_lo(sp.x); a[1] = bf_hi(sp.x);
    a[2] = bf_lo(sp.y); a[3] = bf_hi(sp.y);
    a[4] = bf_lo(sp.z); a[5] = bf_hi(sp.z);
    a[6] = bf_lo(sp.w); a[7] = bf_hi(sp.w);
    int s = base_[row];
    int cd = hist[row];
    int end = s + cd;
    for (; s + 8 <= end; s += 8) {
      uint4 u[8];
#pragma unroll
      for (int k = 0; k < 8; ++k) {
        int idx = sorted[s + k];
        u[k] = h4[(size_t)idx * 16 + ln];
      }
#pragma unroll
      for (int k = 0; k < 8; ++k) {
        a[0] += bf_lo(u[k].x); a[1] += bf_hi(u[k].x);
        a[2] += bf_lo(u[k].y); a[3] += bf_hi(u[k].y);
        a[4] += bf_lo(u[k].z); a[5] += bf_hi(u[k].z);
        a[6] += bf_lo(u[k].w); a[7] += bf_hi(u[k].w);
      }
    }
    for (; s + 4 <= end; s += 4) {
      uint4 u[4];
#pragma unroll
      for (int k = 0; k < 4; ++k) {
        int idx = sorted[s + k];
        u[k] = h4[(size_t)idx * 16 + ln];
      }
#pragma unroll
      for (int k = 0; k < 4; ++k) {
        a[0] += bf_lo(u[k].x); a[1] += bf_hi(u[k].x);
        a[2] += bf_lo(u[k].y); a[3] += bf_hi(u[k].y);
        a[4] += bf_lo(u[k].z); a[5] += bf_hi(u[k].z);
        a[6] += bf_lo(u[k].w); a[7] += bf_hi(u[k].w);
      }
    }
    for (; s < end; ++s) {
      int idx = sorted[s];
      uint4 u = h4[(size_t)idx * 16 + ln];
      a[0] += bf_lo(u.x); a[1] += bf_hi(u.x);
      a[2] += bf_lo(u.y); a[3] += bf_hi(u.y);
      a[4] += bf_lo(u.z); a[5] += bf_hi(u.z);
      a[6] += bf_lo(u.w); a[7] += bf_hi(u.w);
    }
    if (act) {
      float di = rsqrtf((float)cd + 1.0f);
      float4 b0 = ((const float4*)bias)[2 * ln];
      float4 b1 = ((const float4*)bias)[2 * ln + 1];
      f32x4 r0, r1;
      r0[0] = fmaf(a[0], di, b0.x); r0[1] = fmaf(a[1], di, b0.y);
      r0[2] = fmaf(a[2], di, b0.z); r0[3] = fmaf(a[3], di, b0.w);
      r1[0] = fmaf(a[4], di, b1.x); r1[1] = fmaf(a[5], di, b1.y);
      r1[2] = fmaf(a[6], di, b1.z); r1[3] = fmaf(a[7], di, b1.w);
      f32x4* op = (f32x4*)(out + (size_t)node * 128 + ln * 8);
      __builtin_nontemporal_store(r0, op);
      __builtin_nontemporal_store(r1, op + 1);
    }
  }
}

// ======================= round-3 CSR fallback =======================

__global__ void k_init(int* __restrict__ cnt, int n) {
  int i = blockIdx.x * blockDim.x + threadIdx.x;
  if (i < n) cnt[i] = 0;
}

__global__ void k_count4(const int* __restrict__ ei, int* __restrict__ cnt, int E) {
  int i = blockIdx.x * blockDim.x + threadIdx.x;
  int e = i * 4;
  if (e + 3 < E) {
    int4 d = *(const int4*)(ei + E + e);
    atomicAdd(&cnt[d.x], 1); atomicAdd(&cnt[d.y], 1);
    atomicAdd(&cnt[d.z], 1); atomicAdd(&cnt[d.w], 1);
  } else {
    for (; e < E; ++e) atomicAdd(&cnt[ei[E + e]], 1);
  }
}

__global__ void k_scan_local(const int* __restrict__ cnt, int* __restrict__ offs,
                             int* __restrict__ bsums, int n) {
  __shared__ int sh[SCAN_T];
  int t = threadIdx.x;
  int base = blockIdx.x * SCAN_E + t * 4;
  int v0 = 0, v1 = 0, v2 = 0, v3 = 0;
  if (base + 0 < n) v0 = cnt[base + 0];
  if (base + 1 < n) v1 = cnt[base + 1];
  if (base + 2 < n) v2 = cnt[base + 2];
  if (base + 3 < n) v3 = cnt[base + 3];
  int sum = v0 + v1 + v2 + v3;
  sh[t] = sum;
  __syncthreads();
  for (int d = 1; d < SCAN_T; d <<= 1) {
    int xv = (t >= d) ? sh[t - d] : 0;
    __syncthreads();
    sh[t] += xv;
    __syncthreads();
  }
  int run = sh[t] - sum;
  if (base + 0 < n) offs[base + 0] = run; run += v0;
  if (base + 1 < n) offs[base + 1] = run; run += v1;
  if (base + 2 < n) offs[base + 2] = run; run += v2;
  if (base + 3 < n) offs[base + 3] = run;
  if (t == SCAN_T - 1) bsums[blockIdx.x] = sh[t];
}

__global__ void k_scan_bsums(int* __restrict__ bsums, int nb) {
  __shared__ int sh[SCAN_T];
  int t = threadIdx.x;
  int v = (t < nb) ? bsums[t] : 0;
  sh[t] = v;
  __syncthreads();
  for (int d = 1; d < SCAN_T; d <<= 1) {
    int xv = (t >= d) ? sh[t - d] : 0;
    __syncthreads();
    sh[t] += xv;
    __syncthreads();
  }
  if (t < nb) bsums[t] = sh[t] - v;
}

__global__ void k_scan_finish(int* __restrict__ offs, const int* __restrict__ bsums,
                              const int* __restrict__ cnt, int* __restrict__ offs2,
                              float* __restrict__ dinv, int n) {
  int i = blockIdx.x * blockDim.x + threadIdx.x;
  if (i < n) {
    int o = offs[i] + bsums[i / SCAN_E];
    offs[i] = o;
    offs2[i] = o;
    dinv[i] = rsqrtf((float)cnt[i] + 1.0f);
  }
}

__global__ void k_fill4(const int* __restrict__ ei, int* __restrict__ offs2,
                        int* __restrict__ csr, int E) {
  int i = blockIdx.x * blockDim.x + threadIdx.x;
  int e = i * 4;
  if (e + 3 < E) {
    int4 s = *(const int4*)(ei + e);
    int4 d = *(const int4*)(ei + E + e);
    csr[atomicAdd(&offs2[d.x], 1)] = s.x;
    csr[atomicAdd(&offs2[d.y], 1)] = s.y;
    csr[atomicAdd(&offs2[d.z], 1)] = s.z;
    csr[atomicAdd(&offs2[d.w], 1)] = s.w;
  } else {
    for (; e < E; ++e) csr[atomicAdd(&offs2[ei[E + e]], 1)] = ei[e];
  }
}

__global__ void __launch_bounds__(256) k_gemm_h(
    const float* __restrict__ x, const float* __restrict__ W,
    const float* __restrict__ dinv, unsigned short* __restrict__ h, int n) {
  __shared__ alignas(16) unsigned short Wt[128][136];
  int t = threadIdx.x;
#pragma unroll
  for (int p = 0; p < 16; ++p) {
    int task = p * 256 + t;
    int kg = task >> 7, nn = task & 127;
    float w0 = W[(kg * 4 + 0) * 128 + nn];
    float w1 = W[(kg * 4 + 1) * 128 + nn];
    float w2 = W[(kg * 4 + 2) * 128 + nn];
    float w3 = W[(kg * 4 + 3) * 128 + nn];
    ushort4 u;
    u.x = f2bf(w0); u.y = f2bf(w1); u.z = f2bf(w2); u.w = f2bf(w3);
    *(ushort4*)&Wt[nn][kg * 4] = u;
  }
  __syncthreads();
  int w = t >> 6, lane = t & 63;
  int q = lane >> 4, m = lane & 15;
  int r0 = blockIdx.x * 64 + w * 16;
  f32x4 acc[8];
#pragma unroll
  for (int nt = 0; nt < 8; ++nt) acc[nt] = (f32x4){0.f, 0.f, 0.f, 0.f};
  float dscale[4];
#pragma unroll
  for (int rg = 0; rg < 4; ++rg) {
    int r = r0 + q * 4 + rg;
    dscale[rg] = dinv[r < n ? r : n - 1];
  }
#pragma unroll
  for (int ks = 0; ks < 4; ++ks) {
    int row = r0 + m;
    row = row < n ? row : n - 1;
    const float* xp = x + (size_t)row * 128 + ks * 32 + q * 8;
    float4 a0 = *(const float4*)xp;
    float4 a1 = *(const float4*)(xp + 4);
    short8 af;
    af[0] = (short)f2bf(a0.x); af[1] = (short)f2bf(a0.y);
    af[2] = (short)f2bf(a0.z); af[3] = (short)f2bf(a0.w);
    af[4] = (short)f2bf(a1.x); af[5] = (short)f2bf(a1.y);
    af[6] = (short)f2bf(a1.z); af[7] = (short)f2bf(a1.w);
#pragma unroll
    for (int nt = 0; nt < 8; ++nt) {
      short8 bf = *(const short8*)&Wt[nt * 16 + m][ks * 32 + q * 8];
      acc[nt] = __builtin_amdgcn_mfma_f32_16x16x32_bf16(af, bf, acc[nt], 0, 0, 0);
    }
  }
#pragma unroll
  for (int nt = 0; nt < 8; ++nt)
#pragma unroll
    for (int rg = 0; rg < 4; ++rg) {
      int r = r0 + q * 4 + rg;
      if (r < n) h[(size_t)r * 128 + nt * 16 + m] = f2bf(acc[nt][rg] * dscale[rg]);
    }
}

__global__ void __launch_bounds__(256) k_agg_bias_csr(
    const unsigned int* __restrict__ h2, const float* __restrict__ dinv,
    const int* __restrict__ offs, const int* __restrict__ cnt,
    const int* __restrict__ csr, const float* __restrict__ bias,
    float* __restrict__ out, int n) {
  int node = blockIdx.x * WPB + (threadIdx.x >> 6);
  int lane = threadIdx.x & 63;
  if (node >= n) return;
  unsigned int sp = h2[(size_t)node * 64 + lane];
  float ax = bf_lo(sp), ay = bf_hi(sp);
  int s = offs[node];
  int end = s + cnt[node];
  for (; s + 8 <= end; s += 8) {
    int i0 = csr[s + 0], i1 = csr[s + 1], i2 = csr[s + 2], i3 = csr[s + 3];
    int i4 = csr[s + 4], i5 = csr[s + 5], i6 = csr[s + 6], i7 = csr[s + 7];
    unsigned int u0 = h2[(size_t)i0 * 64 + lane];
    unsigned int u1 = h2[(size_t)i1 * 64 + lane];
    unsigned int u2 = h2[(size_t)i2 * 64 + lane];
    unsigned int u3 = h2[(size_t)i3 * 64 + lane];
    unsigned int u4 = h2[(size_t)i4 * 64 + lane];
    unsigned int u5 = h2[(size_t)i5 * 64 + lane];
    unsigned int u6 = h2[(size_t)i6 * 64 + lane];
    unsigned int u7 = h2[(size_t)i7 * 64 + lane];
    ax += (bf_lo(u0) + bf_lo(u1)) + (bf_lo(u2) + bf_lo(u3)) +
          (bf_lo(u4) + bf_lo(u5)) + (bf_lo(u6) + bf_lo(u7));
    ay += (bf_hi(u0) + bf_hi(u1)) + (bf_hi(u2) + bf_hi(u3)) +
          (bf_hi(u4) + bf_hi(u5)) + (bf_hi(u6) + bf_hi(u7));
  }
  for (; s < end; ++s) {
    unsigned int u = h2[(size_t)csr[s] * 64 + lane];
    ax += bf_lo(u); ay += bf_hi(u);
  }
  float di = dinv[node];
  float2 bb = ((const float2*)bias)[lane];
  float2 r;
  r.x = fmaf(ax, di, bb.x);
  r.y = fmaf(ay, di, bb.y);
  ((float2*)out)[(size_t)node * 64 + lane] = r;
}

extern "C" void kernel_launch(void* const* d_in, const int* in_sizes, int n_in,
                              void* d_out, int out_size, void* d_ws, size_t ws_size,
                              hipStream_t stream) {
  const float* x = (const float*)d_in[0];
  const int* ei = (const int*)d_in[1];   // harness delivers integers as int32
  const float* Wm = (const float*)d_in[2];
  const float* bias = (const float*)d_in[3];
  float* out = (float*)d_out;

  int N = in_sizes[0] / 128;
  int E = in_sizes[1] / 2;
  int NB64 = (N + 63) >> 6;
  int NB128 = (N + 127) >> 7;

  int nb_n = (N + 255) / 256;
  int nb_e4 = ((E + 3) / 4 + 255) / 256;

  // ---- v16: bcursor[1024] | pairs[NB128*CAP] | h[N*128 bf16] ----
  size_t off_pairs = 4096;
  size_t off_h = (off_pairs + (size_t)NB128 * CAP * 4 + 255) & ~(size_t)255;
  size_t need16 = off_h + (size_t)N * 256;

  if (ws_size >= need16 && N <= (1 << 17) && NB128 <= 1024) {
    char* p = (char*)d_ws;
    int* bcursor = (int*)p;
    int* pairs = (int*)(p + off_pairs);
    unsigned short* h = (unsigned short*)(p + off_h);

    k_zero<<<4, 256, 0, stream>>>(bcursor, 1024);
    k_scatter<<<(E + SC_T - 1) / SC_T, 512, 0, stream>>>(ei, bcursor, pairs, E, NB128);
    k_gemm_hd<<<NB128, 256, 0, stream>>>(x, Wm, pairs, bcursor, h, N);
    k_sort_agg<<<NB128, 512, 0, stream>>>(pairs, bcursor, (const uint4*)h, bias, out, N);
    return;
  }

  // ---- round-3 CSR fallback ----
  char* p = (char*)d_ws;
  int* cnt = (int*)p;        p += (size_t)N * 4;
  int* offs = (int*)p;       p += (size_t)N * 4;
  int* offs2 = (int*)p;      p += (size_t)N * 4;
  float* dinv = (float*)p;   p += (size_t)N * 4;
  int* bsums = (int*)p;      p += 1024;
  int* csr = (int*)p;        p += (size_t)E * 4;
  unsigned short* h = (unsigned short*)p;

  int nb_scan = (N + SCAN_E - 1) / SCAN_E;

  k_init<<<nb_n, 256, 0, stream>>>(cnt, N);
  k_count4<<<nb_e4, 256, 0, stream>>>(ei, cnt, E);
  k_scan_local<<<nb_scan, SCAN_T, 0, stream>>>(cnt, offs, bsums, N);
  k_scan_bsums<<<1, SCAN_T, 0, stream>>>(bsums, nb_scan);
  k_scan_finish<<<nb_n, 256, 0, stream>>>(offs, bsums, cnt, offs2, dinv, N);
  k_fill4<<<nb_e4, 256, 0, stream>>>(ei, offs2, csr, E);
  k_gemm_h<<<NB64, 256, 0, stream>>>(x, Wm, dinv, h, N);
  k_agg_bias_csr<<<(N + WPB - 1) / WPB, 256, 0, stream>>>(
      (const unsigned int*)h, dinv, offs, cnt, csr, bias, out, N);
}

// Round 14
// 199.511 us; speedup vs baseline: 1.1260x; 1.0311x over previous
//
#include <hip/hip_runtime.h>

// GCNConv: out = A_hat @ x @ W + b, A_hat = D^-1/2 (A + I) D^-1/2
// v17: overlap scatter and GEMM in ONE kernel. dinv scaling moved out of the
// GEMM (h_raw = x@W, unscaled bf16) into the aggregator (per-source
// dinv[src] fma + final dinv[dst] scale), which kills the pairs->GEMM
// dependency: k_scat_gemm runs 196 scatter blocks + 782 pure-GEMM blocks
// concurrently (latency-bound + BW-bound bodies co-scheduled). k_deg (~6us)
// rebuilds global dinv between it and k_sort_agg. Aggregator = v14 gather
// core (at its measured ~2.6TB/s L3 floor) + broadcast dinv[idx] loads.
// (Round-13 resubmit: round-12 bench died on container infra, kernel unrun.)

#define SCAN_T 256
#define SCAN_E 1024
#define WPB 4
#define CAP 2560      // pairs per 128-node bucket (mean 2048, +11 sigma)
#define SC_T 8192     // edges per scatter block -> 196 blocks at E=1.6M

typedef __attribute__((ext_vector_type(8))) short short8;
typedef __attribute__((ext_vector_type(4))) float f32x4;

__device__ __forceinline__ unsigned short f2bf(float f) {
  unsigned int u = __float_as_uint(f);
  u += 0x7FFFu + ((u >> 16) & 1u);   // RNE
  return (unsigned short)(u >> 16);
}
__device__ __forceinline__ float bf_lo(unsigned int u) { return __uint_as_float(u << 16); }
__device__ __forceinline__ float bf_hi(unsigned int u) { return __uint_as_float(u & 0xFFFF0000u); }

// ======================= v17 primary path =======================

__global__ void k_zero(int* __restrict__ p, int m) {
  int i = blockIdx.x * blockDim.x + threadIdx.x;
  if (i < m) p[i] = 0;
}

// Fused scatter + GEMM. blockIdx < NSC: bucket-scatter body (v14 form,
// 512 thr). blockIdx >= NSC: pure bf16 MFMA GEMM h_raw = x @ W (no dinv),
// 128 rows/block, 8 waves. LDS is a union (scatter hist[1024] | Wt tile).
__global__ void __launch_bounds__(512) k_scat_gemm(
    const int* __restrict__ ei, int* __restrict__ bcursor,
    int* __restrict__ pairs, int E, int B, int NSC,
    const float* __restrict__ x, const float* __restrict__ W,
    unsigned short* __restrict__ h, int n) {
  __shared__ alignas(16) unsigned char smem_raw[128 * 136 * 2];
  int t = threadIdx.x;
  if ((int)blockIdx.x < NSC) {
    // ---------------- scatter body ----------------
    int* hist = (int*)smem_raw;
    for (int b = t; b < B; b += 512) hist[b] = 0;
    __syncthreads();
    int e0 = blockIdx.x * SC_T;
    int eend = min(e0 + SC_T, E);
    for (int e = e0 + t * 4; e < eend; e += 2048) {
      if (e + 3 < eend) {
        int4 d = *(const int4*)(ei + E + e);
        atomicAdd(&hist[((unsigned)d.x) >> 7], 1);
        atomicAdd(&hist[((unsigned)d.y) >> 7], 1);
        atomicAdd(&hist[((unsigned)d.z) >> 7], 1);
        atomicAdd(&hist[((unsigned)d.w) >> 7], 1);
      } else {
        for (int q = e; q < eend; ++q) atomicAdd(&hist[((unsigned)ei[E + q]) >> 7], 1);
      }
    }
    __syncthreads();
    for (int b = t; b < B; b += 512) {
      int c = hist[b];
      hist[b] = c ? atomicAdd(&bcursor[b], c) : 0;  // base within bucket
    }
    __syncthreads();
    for (int e = e0 + t * 4; e < eend; e += 2048) {
      if (e + 3 < eend) {
        int4 s = *(const int4*)(ei + e);
        int4 d = *(const int4*)(ei + E + e);
        int b0 = ((unsigned)d.x) >> 7; int p0 = atomicAdd(&hist[b0], 1);
        if (p0 < CAP) pairs[(size_t)b0 * CAP + p0] = ((d.x & 127) << 17) | s.x;
        int b1 = ((unsigned)d.y) >> 7; int p1 = atomicAdd(&hist[b1], 1);
        if (p1 < CAP) pairs[(size_t)b1 * CAP + p1] = ((d.y & 127) << 17) | s.y;
        int b2 = ((unsigned)d.z) >> 7; int p2 = atomicAdd(&hist[b2], 1);
        if (p2 < CAP) pairs[(size_t)b2 * CAP + p2] = ((d.z & 127) << 17) | s.z;
        int b3 = ((unsigned)d.w) >> 7; int p3 = atomicAdd(&hist[b3], 1);
        if (p3 < CAP) pairs[(size_t)b3 * CAP + p3] = ((d.w & 127) << 17) | s.w;
      } else {
        for (int q = e; q < eend; ++q) {
          int dst = ei[E + q], src = ei[q];
          int b0 = ((unsigned)dst) >> 7; int p0 = atomicAdd(&hist[b0], 1);
          if (p0 < CAP) pairs[(size_t)b0 * CAP + p0] = ((dst & 127) << 17) | src;
        }
      }
    }
  } else {
    // ---------------- GEMM body: h_raw = x @ W ----------------
    typedef unsigned short WtRow[136];
    WtRow* Wt = (WtRow*)smem_raw;
    int bb = blockIdx.x - NSC;
    // stage W^T as bf16: read W[kg*4+i][nn] coalesced, write 4 k-consecutive
#pragma unroll
    for (int p = 0; p < 8; ++p) {
      int task = p * 512 + t;
      int kg = task >> 7, nn = task & 127;
      float w0 = W[(kg * 4 + 0) * 128 + nn];
      float w1 = W[(kg * 4 + 1) * 128 + nn];
      float w2 = W[(kg * 4 + 2) * 128 + nn];
      float w3 = W[(kg * 4 + 3) * 128 + nn];
      ushort4 u;
      u.x = f2bf(w0); u.y = f2bf(w1); u.z = f2bf(w2); u.w = f2bf(w3);
      *(ushort4*)&Wt[nn][kg * 4] = u;
    }
    __syncthreads();
    int w = t >> 6, lane = t & 63;
    int q = lane >> 4, m = lane & 15;
    int r0 = (bb << 7) + w * 16;
    f32x4 acc[8];
#pragma unroll
    for (int nt = 0; nt < 8; ++nt) acc[nt] = (f32x4){0.f, 0.f, 0.f, 0.f};
#pragma unroll
    for (int ks = 0; ks < 4; ++ks) {
      int row = r0 + m;
      row = row < n ? row : n - 1;
      const float* xp = x + (size_t)row * 128 + ks * 32 + q * 8;
      float4 a0 = *(const float4*)xp;
      float4 a1 = *(const float4*)(xp + 4);
      short8 af;
      af[0] = (short)f2bf(a0.x); af[1] = (short)f2bf(a0.y);
      af[2] = (short)f2bf(a0.z); af[3] = (short)f2bf(a0.w);
      af[4] = (short)f2bf(a1.x); af[5] = (short)f2bf(a1.y);
      af[6] = (short)f2bf(a1.z); af[7] = (short)f2bf(a1.w);
#pragma unroll
      for (int nt = 0; nt < 8; ++nt) {
        short8 bf = *(const short8*)&Wt[nt * 16 + m][ks * 32 + q * 8];
        acc[nt] = __builtin_amdgcn_mfma_f32_16x16x32_bf16(af, bf, acc[nt], 0, 0, 0);
      }
    }
#pragma unroll
    for (int nt = 0; nt < 8; ++nt)
#pragma unroll
      for (int rg = 0; rg < 4; ++rg) {
        int r = r0 + q * 4 + rg;
        if (r < n) h[(size_t)r * 128 + nt * 16 + m] = f2bf(acc[nt][rg]);
      }
  }
}

// Per-bucket degree count -> dinv. Block b covers nodes b*128..b*128+127.
__global__ void __launch_bounds__(256) k_deg(
    const int* __restrict__ pairs, const int* __restrict__ bcursor,
    float* __restrict__ dinv, int n) {
  __shared__ int hist[128];
  int t = threadIdx.x;
  int b = blockIdx.x;
  if (t < 128) hist[t] = 0;
  __syncthreads();
  int cnt = min(bcursor[b], CAP);
  const int* __restrict__ gp = pairs + (size_t)b * CAP;
  for (int i = t; i < cnt; i += 256) atomicAdd(&hist[gp[i] >> 17], 1);
  __syncthreads();
  if (t < 128) {
    int node = b * 128 + t;
    if (node < n) dinv[node] = rsqrtf((float)hist[t] + 1.0f);
  }
}

// Fused sort + aggregate for a 128-node bucket, 512 threads.
// out = dinv_dst * (sum_src dinv[src]*h_raw[src] + dinv_dst*h_raw[dst]) + b.
__global__ void __launch_bounds__(512) k_sort_agg(
    const int* __restrict__ pairs, const int* __restrict__ bcursor,
    const uint4* __restrict__ h4, const float* __restrict__ dinv,
    const float* __restrict__ bias, float* __restrict__ out, int n) {
  __shared__ int sorted[CAP];
  __shared__ int hist[128], base_[128], cur[128];
  __shared__ int nextn;
  int t = threadIdx.x;
  int b = blockIdx.x;
  if (t < 128) { hist[t] = 0; cur[t] = 0; }
  if (t == 0) nextn = 0;
  __syncthreads();
  int cnt = min(bcursor[b], CAP);
  const int* __restrict__ gp = pairs + (size_t)b * CAP;
  for (int i = t; i < cnt; i += 512) atomicAdd(&hist[gp[i] >> 17], 1);
  __syncthreads();
  // exclusive scan of hist[128] via LDS Hillis-Steele
  if (t < 128) base_[t] = hist[t];
  __syncthreads();
#pragma unroll
  for (int d = 1; d < 128; d <<= 1) {
    int v = (t < 128 && t >= d) ? base_[t - d] : 0;
    __syncthreads();
    if (t < 128) base_[t] += v;
    __syncthreads();
  }
  if (t < 128) base_[t] -= hist[t];
  __syncthreads();
  for (int i = t; i < cnt; i += 512) {
    int p = gp[i];
    int d = p >> 17;
    int pos = base_[d] + atomicAdd(&cur[d], 1);
    sorted[pos] = p & 0x1FFFF;
  }
  __syncthreads();

  // ---- phase 2: gather-aggregate with dynamic node claiming ----
  int lane = t & 63;
  int ln = lane & 15;
  int nbase = b << 7;
  for (;;) {
    int row = 0;
    if (ln == 0) row = atomicAdd(&nextn, 1);
    row = __shfl(row, lane & 48, 64);   // broadcast to the 16-lane group
    if (row >= 128) break;
    int node = nbase + row;
    bool act = node < n;
    int cd = hist[row];
    float did = rsqrtf((float)cd + 1.0f);
    uint4 sp = make_uint4(0u, 0u, 0u, 0u);
    if (act) sp = h4[(size_t)node * 16 + ln];  // self term (x dinv_dst)
    float a[8];
    a[0] = did * bf_lo(sp.x); a[1] = did * bf_hi(sp.x);
    a[2] = did * bf_lo(sp.y); a[3] = did * bf_hi(sp.y);
    a[4] = did * bf_lo(sp.z); a[5] = did * bf_hi(sp.z);
    a[6] = did * bf_lo(sp.w); a[7] = did * bf_hi(sp.w);
    int s = base_[row];
    int end = s + cd;
    for (; s + 8 <= end; s += 8) {
      uint4 u[8]; float dv[8];
#pragma unroll
      for (int k = 0; k < 8; ++k) {
        int idx = sorted[s + k];
        u[k] = h4[(size_t)idx * 16 + ln];
        dv[k] = dinv[idx];
      }
#pragma unroll
      for (int k = 0; k < 8; ++k) {
        a[0] = fmaf(bf_lo(u[k].x), dv[k], a[0]); a[1] = fmaf(bf_hi(u[k].x), dv[k], a[1]);
        a[2] = fmaf(bf_lo(u[k].y), dv[k], a[2]); a[3] = fmaf(bf_hi(u[k].y), dv[k], a[3]);
        a[4] = fmaf(bf_lo(u[k].z), dv[k], a[4]); a[5] = fmaf(bf_hi(u[k].z), dv[k], a[5]);
        a[6] = fmaf(bf_lo(u[k].w), dv[k], a[6]); a[7] = fmaf(bf_hi(u[k].w), dv[k], a[7]);
      }
    }
    for (; s + 4 <= end; s += 4) {
      uint4 u[4]; float dv[4];
#pragma unroll
      for (int k = 0; k < 4; ++k) {
        int idx = sorted[s + k];
        u[k] = h4[(size_t)idx * 16 + ln];
        dv[k] = dinv[idx];
      }
#pragma unroll
      for (int k = 0; k < 4; ++k) {
        a[0] = fmaf(bf_lo(u[k].x), dv[k], a[0]); a[1] = fmaf(bf_hi(u[k].x), dv[k], a[1]);
        a[2] = fmaf(bf_lo(u[k].y), dv[k], a[2]); a[3] = fmaf(bf_hi(u[k].y), dv[k], a[3]);
        a[4] = fmaf(bf_lo(u[k].z), dv[k], a[4]); a[5] = fmaf(bf_hi(u[k].z), dv[k], a[5]);
        a[6] = fmaf(bf_lo(u[k].w), dv[k], a[6]); a[7] = fmaf(bf_hi(u[k].w), dv[k], a[7]);
      }
    }
    for (; s < end; ++s) {
      int idx = sorted[s];
      uint4 u = h4[(size_t)idx * 16 + ln];
      float dv = dinv[idx];
      a[0] = fmaf(bf_lo(u.x), dv, a[0]); a[1] = fmaf(bf_hi(u.x), dv, a[1]);
      a[2] = fmaf(bf_lo(u.y), dv, a[2]); a[3] = fmaf(bf_hi(u.y), dv, a[3]);
      a[4] = fmaf(bf_lo(u.z), dv, a[4]); a[5] = fmaf(bf_hi(u.z), dv, a[5]);
      a[6] = fmaf(bf_lo(u.w), dv, a[6]); a[7] = fmaf(bf_hi(u.w), dv, a[7]);
    }
    if (act) {
      float4 b0 = ((const float4*)bias)[2 * ln];
      float4 b1 = ((const float4*)bias)[2 * ln + 1];
      f32x4 r0, r1;
      r0[0] = fmaf(a[0], did, b0.x); r0[1] = fmaf(a[1], did, b0.y);
      r0[2] = fmaf(a[2], did, b0.z); r0[3] = fmaf(a[3], did, b0.w);
      r1[0] = fmaf(a[4], did, b1.x); r1[1] = fmaf(a[5], did, b1.y);
      r1[2] = fmaf(a[6], did, b1.z); r1[3] = fmaf(a[7], did, b1.w);
      f32x4* op = (f32x4*)(out + (size_t)node * 128 + ln * 8);
      __builtin_nontemporal_store(r0, op);
      __builtin_nontemporal_store(r1, op + 1);
    }
  }
}

// ======================= round-3 CSR fallback =======================

__global__ void k_init(int* __restrict__ cnt, int n) {
  int i = blockIdx.x * blockDim.x + threadIdx.x;
  if (i < n) cnt[i] = 0;
}

__global__ void k_count4(const int* __restrict__ ei, int* __restrict__ cnt, int E) {
  int i = blockIdx.x * blockDim.x + threadIdx.x;
  int e = i * 4;
  if (e + 3 < E) {
    int4 d = *(const int4*)(ei + E + e);
    atomicAdd(&cnt[d.x], 1); atomicAdd(&cnt[d.y], 1);
    atomicAdd(&cnt[d.z], 1); atomicAdd(&cnt[d.w], 1);
  } else {
    for (; e < E; ++e) atomicAdd(&cnt[ei[E + e]], 1);
  }
}

__global__ void k_scan_local(const int* __restrict__ cnt, int* __restrict__ offs,
                             int* __restrict__ bsums, int n) {
  __shared__ int sh[SCAN_T];
  int t = threadIdx.x;
  int base = blockIdx.x * SCAN_E + t * 4;
  int v0 = 0, v1 = 0, v2 = 0, v3 = 0;
  if (base + 0 < n) v0 = cnt[base + 0];
  if (base + 1 < n) v1 = cnt[base + 1];
  if (base + 2 < n) v2 = cnt[base + 2];
  if (base + 3 < n) v3 = cnt[base + 3];
  int sum = v0 + v1 + v2 + v3;
  sh[t] = sum;
  __syncthreads();
  for (int d = 1; d < SCAN_T; d <<= 1) {
    int xv = (t >= d) ? sh[t - d] : 0;
    __syncthreads();
    sh[t] += xv;
    __syncthreads();
  }
  int run = sh[t] - sum;
  if (base + 0 < n) offs[base + 0] = run; run += v0;
  if (base + 1 < n) offs[base + 1] = run; run += v1;
  if (base + 2 < n) offs[base + 2] = run; run += v2;
  if (base + 3 < n) offs[base + 3] = run;
  if (t == SCAN_T - 1) bsums[blockIdx.x] = sh[t];
}

__global__ void k_scan_bsums(int* __restrict__ bsums, int nb) {
  __shared__ int sh[SCAN_T];
  int t = threadIdx.x;
  int v = (t < nb) ? bsums[t] : 0;
  sh[t] = v;
  __syncthreads();
  for (int d = 1; d < SCAN_T; d <<= 1) {
    int xv = (t >= d) ? sh[t - d] : 0;
    __syncthreads();
    sh[t] += xv;
    __syncthreads();
  }
  if (t < nb) bsums[t] = sh[t] - v;
}

__global__ void k_scan_finish(int* __restrict__ offs, const int* __restrict__ bsums,
                              const int* __restrict__ cnt, int* __restrict__ offs2,
                              float* __restrict__ dinv, int n) {
  int i = blockIdx.x * blockDim.x + threadIdx.x;
  if (i < n) {
    int o = offs[i] + bsums[i / SCAN_E];
    offs[i] = o;
    offs2[i] = o;
    dinv[i] = rsqrtf((float)cnt[i] + 1.0f);
  }
}

__global__ void k_fill4(const int* __restrict__ ei, int* __restrict__ offs2,
                        int* __restrict__ csr, int E) {
  int i = blockIdx.x * blockDim.x + threadIdx.x;
  int e = i * 4;
  if (e + 3 < E) {
    int4 s = *(const int4*)(ei + e);
    int4 d = *(const int4*)(ei + E + e);
    csr[atomicAdd(&offs2[d.x], 1)] = s.x;
    csr[atomicAdd(&offs2[d.y], 1)] = s.y;
    csr[atomicAdd(&offs2[d.z], 1)] = s.z;
    csr[atomicAdd(&offs2[d.w], 1)] = s.w;
  } else {
    for (; e < E; ++e) csr[atomicAdd(&offs2[ei[E + e]], 1)] = ei[e];
  }
}

__global__ void __launch_bounds__(256) k_gemm_h(
    const float* __restrict__ x, const float* __restrict__ W,
    const float* __restrict__ dinv, unsigned short* __restrict__ h, int n) {
  __shared__ alignas(16) unsigned short Wt[128][136];
  int t = threadIdx.x;
#pragma unroll
  for (int p = 0; p < 16; ++p) {
    int task = p * 256 + t;
    int kg = task >> 7, nn = task & 127;
    float w0 = W[(kg * 4 + 0) * 128 + nn];
    float w1 = W[(kg * 4 + 1) * 128 + nn];
    float w2 = W[(kg * 4 + 2) * 128 + nn];
    float w3 = W[(kg * 4 + 3) * 128 + nn];
    ushort4 u;
    u.x = f2bf(w0); u.y = f2bf(w1); u.z = f2bf(w2); u.w = f2bf(w3);
    *(ushort4*)&Wt[nn][kg * 4] = u;
  }
  __syncthreads();
  int w = t >> 6, lane = t & 63;
  int q = lane >> 4, m = lane & 15;
  int r0 = blockIdx.x * 64 + w * 16;
  f32x4 acc[8];
#pragma unroll
  for (int nt = 0; nt < 8; ++nt) acc[nt] = (f32x4){0.f, 0.f, 0.f, 0.f};
  float dscale[4];
#pragma unroll
  for (int rg = 0; rg < 4; ++rg) {
    int r = r0 + q * 4 + rg;
    dscale[rg] = dinv[r < n ? r : n - 1];
  }
#pragma unroll
  for (int ks = 0; ks < 4; ++ks) {
    int row = r0 + m;
    row = row < n ? row : n - 1;
    const float* xp = x + (size_t)row * 128 + ks * 32 + q * 8;
    float4 a0 = *(const float4*)xp;
    float4 a1 = *(const float4*)(xp + 4);
    short8 af;
    af[0] = (short)f2bf(a0.x); af[1] = (short)f2bf(a0.y);
    af[2] = (short)f2bf(a0.z); af[3] = (short)f2bf(a0.w);
    af[4] = (short)f2bf(a1.x); af[5] = (short)f2bf(a1.y);
    af[6] = (short)f2bf(a1.z); af[7] = (short)f2bf(a1.w);
#pragma unroll
    for (int nt = 0; nt < 8; ++nt) {
      short8 bf = *(const short8*)&Wt[nt * 16 + m][ks * 32 + q * 8];
      acc[nt] = __builtin_amdgcn_mfma_f32_16x16x32_bf16(af, bf, acc[nt], 0, 0, 0);
    }
  }
#pragma unroll
  for (int nt = 0; nt < 8; ++nt)
#pragma unroll
    for (int rg = 0; rg < 4; ++rg) {
      int r = r0 + q * 4 + rg;
      if (r < n) h[(size_t)r * 128 + nt * 16 + m] = f2bf(acc[nt][rg] * dscale[rg]);
    }
}

__global__ void __launch_bounds__(256) k_agg_bias_csr(
    const unsigned int* __restrict__ h2, const float* __restrict__ dinv,
    const int* __restrict__ offs, const int* __restrict__ cnt,
    const int* __restrict__ csr, const float* __restrict__ bias,
    float* __restrict__ out, int n) {
  int node = blockIdx.x * WPB + (threadIdx.x >> 6);
  int lane = threadIdx.x & 63;
  if (node >= n) return;
  unsigned int sp = h2[(size_t)node * 64 + lane];
  float ax = bf_lo(sp), ay = bf_hi(sp);
  int s = offs[node];
  int end = s + cnt[node];
  for (; s + 8 <= end; s += 8) {
    int i0 = csr[s + 0], i1 = csr[s + 1], i2 = csr[s + 2], i3 = csr[s + 3];
    int i4 = csr[s + 4], i5 = csr[s + 5], i6 = csr[s + 6], i7 = csr[s + 7];
    unsigned int u0 = h2[(size_t)i0 * 64 + lane];
    unsigned int u1 = h2[(size_t)i1 * 64 + lane];
    unsigned int u2 = h2[(size_t)i2 * 64 + lane];
    unsigned int u3 = h2[(size_t)i3 * 64 + lane];
    unsigned int u4 = h2[(size_t)i4 * 64 + lane];
    unsigned int u5 = h2[(size_t)i5 * 64 + lane];
    unsigned int u6 = h2[(size_t)i6 * 64 + lane];
    unsigned int u7 = h2[(size_t)i7 * 64 + lane];
    ax += (bf_lo(u0) + bf_lo(u1)) + (bf_lo(u2) + bf_lo(u3)) +
          (bf_lo(u4) + bf_lo(u5)) + (bf_lo(u6) + bf_lo(u7));
    ay += (bf_hi(u0) + bf_hi(u1)) + (bf_hi(u2) + bf_hi(u3)) +
          (bf_hi(u4) + bf_hi(u5)) + (bf_hi(u6) + bf_hi(u7));
  }
  for (; s < end; ++s) {
    unsigned int u = h2[(size_t)csr[s] * 64 + lane];
    ax += bf_lo(u); ay += bf_hi(u);
  }
  float di = dinv[node];
  float2 bb = ((const float2*)bias)[lane];
  float2 r;
  r.x = fmaf(ax, di, bb.x);
  r.y = fmaf(ay, di, bb.y);
  ((float2*)out)[(size_t)node * 64 + lane] = r;
}

extern "C" void kernel_launch(void* const* d_in, const int* in_sizes, int n_in,
                              void* d_out, int out_size, void* d_ws, size_t ws_size,
                              hipStream_t stream) {
  const float* x = (const float*)d_in[0];
  const int* ei = (const int*)d_in[1];   // harness delivers integers as int32
  const float* Wm = (const float*)d_in[2];
  const float* bias = (const float*)d_in[3];
  float* out = (float*)d_out;

  int N = in_sizes[0] / 128;
  int E = in_sizes[1] / 2;
  int NB64 = (N + 63) >> 6;
  int NB128 = (N + 127) >> 7;

  int nb_n = (N + 255) / 256;
  int nb_e4 = ((E + 3) / 4 + 255) / 256;

  // ---- v17: bcursor[1024] | pairs[NB128*CAP] | h[N*128 bf16] | dinv[N] ----
  size_t off_pairs = 4096;
  size_t off_h = (off_pairs + (size_t)NB128 * CAP * 4 + 255) & ~(size_t)255;
  size_t off_dinv = (off_h + (size_t)N * 256 + 255) & ~(size_t)255;
  size_t need17 = off_dinv + (size_t)N * 4;

  if (ws_size >= need17 && N <= (1 << 17) && NB128 <= 1024) {
    char* p = (char*)d_ws;
    int* bcursor = (int*)p;
    int* pairs = (int*)(p + off_pairs);
    unsigned short* h = (unsigned short*)(p + off_h);
    float* dinv = (float*)(p + off_dinv);

    int NSC = (E + SC_T - 1) / SC_T;
    k_zero<<<4, 256, 0, stream>>>(bcursor, 1024);
    k_scat_gemm<<<NSC + NB128, 512, 0, stream>>>(
        ei, bcursor, pairs, E, NB128, NSC, x, Wm, h, N);
    k_deg<<<NB128, 256, 0, stream>>>(pairs, bcursor, dinv, N);
    k_sort_agg<<<NB128, 512, 0, stream>>>(
        pairs, bcursor, (const uint4*)h, dinv, bias, out, N);
    return;
  }

  // ---- round-3 CSR fallback ----
  char* p = (char*)d_ws;
  int* cnt = (int*)p;        p += (size_t)N * 4;
  int* offs = (int*)p;       p += (size_t)N * 4;
  int* offs2 = (int*)p;      p += (size_t)N * 4;
  float* dinv = (float*)p;   p += (size_t)N * 4;
  int* bsums = (int*)p;      p += 1024;
  int* csr = (int*)p;        p += (size_t)E * 4;
  unsigned short* h = (unsigned short*)p;

  int nb_scan = (N + SCAN_E - 1) / SCAN_E;

  k_init<<<nb_n, 256, 0, stream>>>(cnt, N);
  k_count4<<<nb_e4, 256, 0, stream>>>(ei, cnt, E);
  k_scan_local<<<nb_scan, SCAN_T, 0, stream>>>(cnt, offs, bsums, N);
  k_scan_bsums<<<1, SCAN_T, 0, stream>>>(bsums, nb_scan);
  k_scan_finish<<<nb_n, 256, 0, stream>>>(offs, bsums, cnt, offs2, dinv, N);
  k_fill4<<<nb_e4, 256, 0, stream>>>(ei, offs2, csr, E);
  k_gemm_h<<<NB64, 256, 0, stream>>>(x, Wm, dinv, h, N);
  k_agg_bias_csr<<<(N + WPB - 1) / WPB, 256, 0, stream>>>(
      (const unsigned int*)h, dinv, offs, cnt, csr, bias, out, N);
}